// Round 1
// baseline (152.741 us; speedup 1.0000x reference)
//
#include <hip/hip_runtime.h>
#include <hip/hip_bf16.h>
#include <math.h>

#define INPUT_DIM 256
#define OUT_DIM   256
#define NDEG      8                    // degree+1
#define KTOT      (INPUT_DIM * NDEG)   // 2048
#define NROWS     (16 * 2048)          // 32768

#define BM  128
#define BN  128
#define BK  64     // 8 inputs * 8 degrees per K-chunk
#define LDT 72     // padded LDS row stride in bf16 elems (144 B = 9*16B -> 2-way-only conflicts)

typedef __bf16 bf16x8 __attribute__((ext_vector_type(8)));
typedef float  f32x4  __attribute__((ext_vector_type(4)));

// ---------------------------------------------------------------------------
// Kernel 1: reorder coeffs  C[i][o][d] (fp32)  ->  Bt[o][i*8+d] (bf16)
// Bt is B^T: [OUT_DIM][KTOT]. Reads are fully coalesced (thread g reads 32 B
// contiguous at C + i*2048 + o*8); writes are scattered 16 B (1 MB total, cheap).
// ---------------------------------------------------------------------------
__global__ __launch_bounds__(256) void reorder_coeffs(const float* __restrict__ C,
                                                      __bf16* __restrict__ Bt) {
    int g = blockIdx.x * 256 + threadIdx.x;   // 65536 = 256 i * 256 o
    int i = g >> 8;
    int o = g & 255;
    const float4* src = (const float4*)(C + (size_t)i * (OUT_DIM * NDEG) + o * NDEG);
    float4 a = src[0];
    float4 b = src[1];
    bf16x8 v;
    v[0] = (__bf16)a.x; v[1] = (__bf16)a.y; v[2] = (__bf16)a.z; v[3] = (__bf16)a.w;
    v[4] = (__bf16)b.x; v[5] = (__bf16)b.y; v[6] = (__bf16)b.z; v[7] = (__bf16)b.w;
    *(bf16x8*)(Bt + (size_t)o * KTOT + i * NDEG) = v;   // 16B-aligned
}

// ---------------------------------------------------------------------------
// Kernel 2: fused tanh + Hermite featurize + bf16 MFMA GEMM.
// Block tile 128x128, 4 waves of 64x64 (4x4 grid of 16x16x32 MFMA frags).
// A tile computed in-kernel (fp32 recurrence, bf16 pack) into padded LDS;
// B^T tile staged from the reordered Bt (L2-resident, 1 MB).
// ---------------------------------------------------------------------------
__global__ __launch_bounds__(256, 2) void hermite_mfma(const float* __restrict__ x,
                                                       const __bf16* __restrict__ Bt,
                                                       float* __restrict__ out) {
    __shared__ __align__(16) __bf16 Alds[BM * LDT];   // 18432 B
    __shared__ __align__(16) __bf16 Blds[BN * LDT];   // 18432 B

    const int tid  = threadIdx.x;
    const int bm   = blockIdx.x;   // 0..255  (M blocks)
    const int bn   = blockIdx.y;   // 0..1    (N blocks)
    const int wave = tid >> 6;
    const int lane = tid & 63;
    const int wr   = (wave >> 1) * 64;   // wave row origin in tile
    const int wc   = (wave & 1) * 64;    // wave col origin in tile
    const int lrow = lane & 15;          // m (A) / n (B) within 16
    const int quad = lane >> 4;          // 0..3

    // A staging: thread -> (row am, 4 consecutive inputs starting at ah)
    const int am = tid >> 1;             // 0..127
    const int ah = (tid & 1) * 4;        // 0 or 4
    const float* xrow = x + (size_t)(bm * BM + am) * INPUT_DIM;

    // B staging: thread -> (row bo(+32q), 8-elem segment bseg)
    const int bo   = tid >> 3;           // 0..31
    const int bseg = (tid & 7) * 8;      // 0..56

    f32x4 acc[4][4] = {};

    for (int kc = 0; kc < KTOT / BK; ++kc) {
        const int i0 = kc * 8;           // first input index of this chunk

        // ---- stage A: tanh + physicists' Hermite recurrence (fp32), pack bf16 ----
        float4 xv = *(const float4*)(xrow + i0 + ah);
        #pragma unroll
        for (int j = 0; j < 4; ++j) {
            float xs = (&xv.x)[j];
            // tanh(x) = 1 - 2/(e^{2x}+1): robust for all x (overflow -> t=1)
            float e = __expf(2.0f * xs);
            float t = 1.0f - 2.0f / (e + 1.0f);
            bf16x8 v;
            float hm2 = 1.0f;            // H_0
            float hm1 = 2.0f * t;        // H_1
            v[0] = (__bf16)hm2;
            v[1] = (__bf16)hm1;
            #pragma unroll
            for (int d = 2; d < 8; ++d) {
                float h = 2.0f * t * hm1 - 2.0f * (float)(d - 1) * hm2;
                v[d] = (__bf16)h;
                hm2 = hm1; hm1 = h;
            }
            *(bf16x8*)(&Alds[am * LDT + (ah + j) * 8]) = v;   // 16B-aligned
        }

        // ---- stage B^T chunk: 128 rows x 64 k (16 KB) via 16B register loads ----
        const int k0 = kc * BK;
        #pragma unroll
        for (int q = 0; q < 4; ++q) {
            int o = bo + 32 * q;
            uint4 bv = *(const uint4*)(Bt + (size_t)(bn * BN + o) * KTOT + k0 + bseg);
            *(uint4*)(&Blds[o * LDT + bseg]) = bv;
        }

        __syncthreads();

        // ---- MFMA: 2 k-steps of 32, 4x4 frags per wave ----
        #pragma unroll
        for (int ki = 0; ki < 2; ++ki) {
            bf16x8 af[4], bfr[4];
            #pragma unroll
            for (int mi = 0; mi < 4; ++mi)
                af[mi] = *(const bf16x8*)(&Alds[(wr + mi * 16 + lrow) * LDT + ki * 32 + quad * 8]);
            #pragma unroll
            for (int ni = 0; ni < 4; ++ni)
                bfr[ni] = *(const bf16x8*)(&Blds[(wc + ni * 16 + lrow) * LDT + ki * 32 + quad * 8]);
            #pragma unroll
            for (int mi = 0; mi < 4; ++mi)
                #pragma unroll
                for (int ni = 0; ni < 4; ++ni)
                    acc[mi][ni] = __builtin_amdgcn_mfma_f32_16x16x32_bf16(
                        af[mi], bfr[ni], acc[mi][ni], 0, 0, 0);
        }

        __syncthreads();
    }

    // ---- epilogue: C/D layout col=lane&15, row=quad*4+reg (m89-verified) ----
    #pragma unroll
    for (int mi = 0; mi < 4; ++mi) {
        #pragma unroll
        for (int r = 0; r < 4; ++r) {
            int row = bm * BM + wr + mi * 16 + quad * 4 + r;
            float* orow = out + (size_t)row * OUT_DIM + bn * BN + wc + lrow;
            #pragma unroll
            for (int ni = 0; ni < 4; ++ni)
                orow[ni * 16] = acc[mi][ni][r];
        }
    }
}

// ---------------------------------------------------------------------------
extern "C" void kernel_launch(void* const* d_in, const int* in_sizes, int n_in,
                              void* d_out, int out_size, void* d_ws, size_t ws_size,
                              hipStream_t stream) {
    const float* x = (const float*)d_in[0];          // [16,2048,256] fp32
    const float* C = (const float*)d_in[1];          // [256,256,8]  fp32
    float* out = (float*)d_out;                      // [16,2048,256] fp32
    __bf16* Bt = (__bf16*)d_ws;                      // [256][2048] bf16, 1 MB scratch

    reorder_coeffs<<<dim3((INPUT_DIM * OUT_DIM) / 256), dim3(256), 0, stream>>>(C, Bt);
    hermite_mfma<<<dim3(NROWS / BM, OUT_DIM / BN), dim3(256), 0, stream>>>(x, Bt, out);
}